// Round 1
// baseline (573.114 us; speedup 1.0000x reference)
//
#include <hip/hip_runtime.h>
#include <stdint.h>

#define LBL 50
#define NL 52
#define NEGV (-100.0f)
#define L2E 1.4426950408889634f
#define BB 128
#define SS 512
#define DD 1024

typedef __attribute__((ext_vector_type(8))) short short8;
typedef __attribute__((ext_vector_type(4))) float float4v;

static __device__ __forceinline__ unsigned int f2bf(float f) {
    union { float f; unsigned int u; } v; v.f = f;
    unsigned int r = v.u + 0x7fffu + ((v.u >> 16) & 1u);
    return r >> 16;
}

static __device__ __forceinline__ float readlane0(float x) {
    return __int_as_float(__builtin_amdgcn_readfirstlane(__float_as_int(x)));
}

// ---------------------------------------------------------------------------
// Kernel 1: logits[r, l] = sum_d A[r,d]*W[l,d] + bias[l]   (r = b*S+s)
// bf16 MFMA, memory-bound on A (256 MB). Block: 64 rows x 64 cols (50 valid).
// ---------------------------------------------------------------------------
__global__ __launch_bounds__(256) void gemm_logits(
    const float* __restrict__ A,    // [65536,1024]
    const float* __restrict__ W,    // [50,1024]
    const float* __restrict__ bias, // [50]
    float* __restrict__ out)        // [65536,50]
{
    // LDS tiles: 64 rows x 64 k (bf16), row stride 72 (pad -> 2-way-free banks, 16B aligned)
    __shared__ __align__(16) unsigned short As[64 * 72];
    __shared__ __align__(16) unsigned short Ws[64 * 72];

    const int tid  = threadIdx.x;
    const int m0   = blockIdx.x * 64;
    const int lane = tid & 63;
    const int wv   = tid >> 6;       // wave id 0..3 -> row tile
    const int mrow = lane & 15;
    const int quad = lane >> 4;

    float4v acc[4];
#pragma unroll
    for (int i = 0; i < 4; ++i) acc[i] = (float4v){0.f, 0.f, 0.f, 0.f};

    for (int kc = 0; kc < DD; kc += 64) {
        __syncthreads();
        // stage A: 64 rows x 16 float4; 256 threads x 4
#pragma unroll
        for (int p = 0; p < 4; ++p) {
            int idx = tid + p * 256;          // 0..1023
            int r = idx >> 4, kq = idx & 15;
            const float4 v = *(const float4*)(A + (size_t)(m0 + r) * DD + kc + kq * 4);
            unsigned int lo = f2bf(v.x) | (f2bf(v.y) << 16);
            unsigned int hi = f2bf(v.z) | (f2bf(v.w) << 16);
            uint2 pk; pk.x = lo; pk.y = hi;
            *(uint2*)&As[r * 72 + kq * 4] = pk;
        }
        // stage W: rows >= 50 are zero
#pragma unroll
        for (int p = 0; p < 4; ++p) {
            int idx = tid + p * 256;
            int r = idx >> 4, kq = idx & 15;
            float4 v = {0.f, 0.f, 0.f, 0.f};
            if (r < LBL) v = *(const float4*)(W + (size_t)r * DD + kc + kq * 4);
            unsigned int lo = f2bf(v.x) | (f2bf(v.y) << 16);
            unsigned int hi = f2bf(v.z) | (f2bf(v.w) << 16);
            uint2 pk; pk.x = lo; pk.y = hi;
            *(uint2*)&Ws[r * 72 + kq * 4] = pk;
        }
        __syncthreads();
#pragma unroll
        for (int ks = 0; ks < 64; ks += 32) {
            // a_frag: A[m = lane&15][k = quad*8 + j]
            short8 a = *(const short8*)&As[(wv * 16 + mrow) * 72 + ks + quad * 8];
#pragma unroll
            for (int nt = 0; nt < 4; ++nt) {
                // b_frag: B[k][n] = W[n][k], n = lane&15
                short8 b = *(const short8*)&Ws[(nt * 16 + mrow) * 72 + ks + quad * 8];
                acc[nt] = __builtin_amdgcn_mfma_f32_16x16x32_bf16(a, b, acc[nt], 0, 0, 0);
            }
        }
    }
    // epilogue: D[row = quad*4 + r][col = lane&15]
#pragma unroll
    for (int nt = 0; nt < 4; ++nt) {
        int col = nt * 16 + mrow;
        if (col < LBL) {
            float bv = bias[col];
#pragma unroll
            for (int r = 0; r < 4; ++r) {
                int row = m0 + wv * 16 + quad * 4 + r;
                out[(size_t)row * LBL + col] = acc[nt][r] + bv;
            }
        }
    }
}

// ---------------------------------------------------------------------------
// Kernel 2: per-batch CRF forward recursion (wave 0) + gold score (wave 1)
// alpha'[i] = logit[i] + M + log(sum_j e^{alpha_j - M} * e^{T[i,j]})
// All in base-2 domain: a2 = alpha*log2(e). M = lane-0 value (overflow-safe).
// ---------------------------------------------------------------------------
__global__ __launch_bounds__(128) void crf_seq(
    const float* __restrict__ logits, // [B*S, 50], base-e
    const float* __restrict__ T,      // [52,52]
    const int*   __restrict__ lens,   // [128]
    const int*   __restrict__ labels, // [128,512]
    float* __restrict__ out)          // [1], pre-zeroed
{
    const int b    = blockIdx.x;
    const int tid  = threadIdx.x;
    const int lane = tid & 63;
    const int len  = lens[b];
    const size_t bo = (size_t)b * SS;

    __shared__ __align__(16) float E_sh[64];
    __shared__ float red[2];

    if (tid < 64) {
        // ---------------- wave 0: recursion ----------------
        const int i = (lane < NL) ? lane : (NL - 1);
        float ET[NL]; // e^{T[i][j]} in registers
#pragma unroll
        for (int jq = 0; jq < 13; ++jq) {
            float4 tv = *(const float4*)(T + i * NL + jq * 4);
            ET[jq * 4 + 0] = __builtin_amdgcn_exp2f(tv.x * L2E);
            ET[jq * 4 + 1] = __builtin_amdgcn_exp2f(tv.y * L2E);
            ET[jq * 4 + 2] = __builtin_amdgcn_exp2f(tv.z * L2E);
            ET[jq * 4 + 3] = __builtin_amdgcn_exp2f(tv.w * L2E);
        }
        // t = 0 analytically: alpha1[i] = logit0[i] + T[i][START]
        float lg0 = (lane < LBL) ? logits[bo * LBL + lane] : NEGV;
        float tS  = T[i * NL + LBL]; // col START=50
        float a2  = (lane < NL) ? (lg0 + tS) * L2E : -1e30f;
        float M2  = readlane0(a2);

        // prefetch distance 2 (indices clamped to len-1, always in-bounds)
        int tA = (1 < len) ? 1 : len - 1;
        int tB = (2 < len) ? 2 : len - 1;
        float lgA = (lane < LBL) ? logits[(bo + tA) * LBL + lane] : NEGV;
        float lgB = (lane < LBL) ? logits[(bo + tB) * LBL + lane] : NEGV;

        for (int t = 1; t < len; ++t) {
            float lgcur = lgA;
            lgA = lgB;
            int tp = (t + 2 < len) ? (t + 2) : (len - 1);
            lgB = (lane < LBL) ? logits[(bo + tp) * LBL + lane] : NEGV;

            float E = __builtin_amdgcn_exp2f(a2 - M2);
            E_sh[lane] = E;
            __builtin_amdgcn_wave_barrier();

            float s0 = 0.f, s1 = 0.f, s2 = 0.f, s3 = 0.f;
#pragma unroll
            for (int jq = 0; jq < 13; ++jq) {
                float4v e4 = *(const float4v*)&E_sh[jq * 4];
                s0 += e4.x * ET[jq * 4 + 0];
                s1 += e4.y * ET[jq * 4 + 1];
                s2 += e4.z * ET[jq * 4 + 2];
                s3 += e4.w * ET[jq * 4 + 3];
            }
            __builtin_amdgcn_wave_barrier();
            float sum = (s0 + s1) + (s2 + s3);
            float a2n = lgcur * L2E + M2 + __builtin_amdgcn_logf(sum);
            a2 = (lane < NL) ? a2n : -1e30f;
            M2 = readlane0(a2);
        }

        // norm = lse_j(alpha_j + T[END][j])
        float v = 0.f;
        if (lane < NL) {
            float tE = T[(NL - 1) * NL + lane]; // row END=51
            v = __builtin_amdgcn_exp2f(a2 + tE * L2E - M2);
        }
#pragma unroll
        for (int m = 32; m; m >>= 1) v += __shfl_xor(v, m, 64);
        float norm_e = (M2 + __builtin_amdgcn_logf(v)) * (1.0f / L2E);
        if (lane == 0) red[0] = norm_e;
    } else {
        // ---------------- wave 1: gold score ----------------
        float un = 0.f, bi = 0.f;
        for (int t = lane; t < len; t += 64) {
            int lab = labels[bo + t];
            un += logits[(bo + t) * LBL + lab];
            int prev = (t == 0) ? LBL : labels[bo + t - 1]; // START=50
            bi += T[lab * NL + prev];
        }
        float g = un + bi;
#pragma unroll
        for (int m = 32; m; m >>= 1) g += __shfl_xor(g, m, 64);
        if (lane == 0) {
            int lastLab = labels[bo + len - 1];
            g += T[(NL - 1) * NL + lastLab]; // T[END, l_{len-1}]
            red[1] = g;
        }
    }
    __syncthreads();
    if (tid == 0) atomicAdd(out, red[0] - red[1]); // loss = sum(norm - gold)
}

// ---------------------------------------------------------------------------
extern "C" void kernel_launch(void* const* d_in, const int* in_sizes, int n_in,
                              void* d_out, int out_size, void* d_ws, size_t ws_size,
                              hipStream_t stream) {
    const float* A      = (const float*)d_in[0]; // inputs [128,512,1024]
    const float* W      = (const float*)d_in[1]; // [50,1024]
    const float* bias   = (const float*)d_in[2]; // [50]
    const float* T      = (const float*)d_in[3]; // [52,52]
    const int*   lens   = (const int*)d_in[4];   // [128]
    const int*   labels = (const int*)d_in[5];   // [128,512]
    float* out = (float*)d_out;
    float* logits = (float*)d_ws;                // 65536*50*4 = 13.1 MB

    hipMemsetAsync(d_out, 0, sizeof(float), stream);
    gemm_logits<<<dim3((BB * SS) / 64), dim3(256), 0, stream>>>(A, W, bias, logits);
    crf_seq<<<dim3(BB), dim3(128), 0, stream>>>(logits, T, lens, labels, out);
}